// Round 1
// baseline (3577.676 us; speedup 1.0000x reference)
//
#include <hip/hip_runtime.h>
#include <math.h>

#define D_IN 5
#define H 64

// ---------------- input projection: out[i,h] = b[h] + sum_d x[i,d]*W[d,h] ----------------
__global__ __launch_bounds__(256) void proj_kernel(
    const float* __restrict__ x, const float* __restrict__ W,
    const float* __restrict__ b, float* __restrict__ out, int n) {
  __shared__ float Ws[D_IN * H];
  __shared__ float bs[H];
  int t = threadIdx.x;
  for (int i = t; i < D_IN * H; i += 256) Ws[i] = W[i];
  if (t < H) bs[t] = b[t];
  __syncthreads();
  int idx = blockIdx.x * 256 + t;
  int node = idx >> 6;
  int h = idx & 63;
  if (node >= n) return;
  const float* xr = x + (size_t)node * D_IN;
  float acc = bs[h];
#pragma unroll
  for (int d = 0; d < D_IN; ++d) acc = fmaf(xr[d], Ws[d * H + h], acc);
  out[(size_t)node * H + h] = acc;
}

// ---------------- CSR build ----------------
__global__ __launch_bounds__(256) void degree_kernel(
    const int* __restrict__ src, const int* __restrict__ dst,
    int* cur_mch, int* cur_mft, int E) {
  int e = blockIdx.x * 256 + threadIdx.x;
  if (e >= E) return;
  atomicAdd(&cur_mch[src[e]], 1);
  atomicAdd(&cur_mft[dst[e]], 1);
}

// exclusive scan; block 0 scans (deg0,n0)->off0, block 1 scans (deg1,n1)->off1
__global__ __launch_bounds__(1024) void scan_kernel(
    const int* __restrict__ deg0, int* __restrict__ off0, int n0,
    const int* __restrict__ deg1, int* __restrict__ off1, int n1) {
  const int* deg = blockIdx.x ? deg1 : deg0;
  int* off = blockIdx.x ? off1 : off0;
  int n = blockIdx.x ? n1 : n0;
  __shared__ int tmp[1024];
  __shared__ int carry;
  int t = threadIdx.x;
  if (t == 0) carry = 0;
  __syncthreads();
  for (int base = 0; base < n; base += 1024) {
    int i = base + t;
    int v = (i < n) ? deg[i] : 0;
    tmp[t] = v;
    __syncthreads();
    for (int s = 1; s < 1024; s <<= 1) {
      int add = (t >= s) ? tmp[t - s] : 0;
      __syncthreads();
      tmp[t] += add;
      __syncthreads();
    }
    int incl = tmp[t];
    if (i < n) off[i] = carry + incl - v;
    __syncthreads();
    if (t == 1023) carry = carry + tmp[1023];
    __syncthreads();
  }
  if (t == 0) off[n] = carry;
}

__global__ __launch_bounds__(256) void initcur_kernel(
    const int* __restrict__ off0, int* __restrict__ cur0, int n0,
    const int* __restrict__ off1, int* __restrict__ cur1, int n1) {
  int i = blockIdx.x * 256 + threadIdx.x;
  if (i < n0) cur0[i] = off0[i];
  if (i < n1) cur1[i] = off1[i];
}

__global__ __launch_bounds__(256) void fill_kernel(
    const int* __restrict__ src, const int* __restrict__ dst,
    int* cur_mch, int* cur_mft,
    int* __restrict__ col_mch, int* __restrict__ col_mft, int E) {
  int e = blockIdx.x * 256 + threadIdx.x;
  if (e >= E) return;
  int s = src[e], d = dst[e];
  col_mft[atomicAdd(&cur_mft[d], 1)] = s;   // MFT row d gathers MCH node s
  col_mch[atomicAdd(&cur_mch[s], 1)] = d;   // MCH row s gathers MFT node d
}

// ---------------- fused SAGE: out = act( mean_agg @ Wl + bl + root @ Wr ) ----------------
// one wave per dst node; lane = output feature h
template <bool RELU>
__global__ __launch_bounds__(256) void sage_kernel(
    const float* __restrict__ xsrc, const float* __restrict__ xdst,
    const int* __restrict__ off, const int* __restrict__ col,
    const float* __restrict__ Wl, const float* __restrict__ bl,
    const float* __restrict__ Wr,
    float* __restrict__ out, int n_dst) {
  __shared__ float Wls[H * H];
  __shared__ float Wrs[H * H];
  __shared__ float bls[H];
  int t = threadIdx.x;
  for (int i = t; i < H * H; i += 256) {
    Wls[i] = Wl[i];
    Wrs[i] = Wr[i];
  }
  if (t < H) bls[t] = bl[t];
  __syncthreads();
  int wave = t >> 6, lane = t & 63;
  int node = blockIdx.x * 4 + wave;
  if (node >= n_dst) return;
  int beg = off[node], end = off[node + 1];
  float acc = 0.f;
  for (int j = beg; j < end; ++j) {
    int idx = col[j];
    acc += xsrc[(size_t)idx * H + lane];
  }
  float invd = (end > beg) ? 1.f / (float)(end - beg) : 1.f;
  float mean = acc * invd;
  float root = xdst[(size_t)node * H + lane];
  float o = bls[lane];
#pragma unroll 8
  for (int k = 0; k < H; ++k) {
    float mk = __shfl(mean, k);
    float rk = __shfl(root, k);
    o = fmaf(mk, Wls[k * H + lane], o);
    o = fmaf(rk, Wrs[k * H + lane], o);
  }
  if (RELU) o = fmaxf(o, 0.f);
  out[(size_t)node * H + lane] = o;
}

// ---------------- edge classifier: sigmoid(relu([mch2[s],mft2[d]] @ W1 + b1) @ W2 + b2) ----------------
// one wave per edge; lane = hidden feature h
__global__ __launch_bounds__(256) void edge_mlp_kernel(
    const float* __restrict__ mch2, const float* __restrict__ mft2,
    const int* __restrict__ src, const int* __restrict__ dst,
    const float* __restrict__ W1, const float* __restrict__ b1,
    const float* __restrict__ W2, const float* __restrict__ b2,
    float* __restrict__ out, int E) {
  __shared__ float W1s[2 * H * H];  // 32 KiB
  __shared__ float b1s[H];
  __shared__ float W2s[H];
  int t = threadIdx.x;
  for (int i = t; i < 2 * H * H; i += 256) W1s[i] = W1[i];
  if (t < H) {
    b1s[t] = b1[t];
    W2s[t] = W2[t];
  }
  __syncthreads();
  int wave = t >> 6, lane = t & 63;
  int e = blockIdx.x * 4 + wave;
  if (e >= E) return;
  int s = src[e], d = dst[e];
  float a = mch2[(size_t)s * H + lane];
  float b = mft2[(size_t)d * H + lane];
  float g = b1s[lane];
#pragma unroll 8
  for (int k = 0; k < H; ++k) {
    float ak = __shfl(a, k);
    float bk = __shfl(b, k);
    g = fmaf(ak, W1s[k * H + lane], g);
    g = fmaf(bk, W1s[(H + k) * H + lane], g);
  }
  g = fmaxf(g, 0.f);
  float p = g * W2s[lane];
#pragma unroll
  for (int o = 32; o; o >>= 1) p += __shfl_xor(p, o);
  if (lane == 0) out[e] = 1.f / (1.f + expf(-(p + b2[0])));
}

extern "C" void kernel_launch(void* const* d_in, const int* in_sizes, int n_in,
                              void* d_out, int out_size, void* d_ws, size_t ws_size,
                              hipStream_t stream) {
  const float* x_mch = (const float*)d_in[0];
  const float* x_mft = (const float*)d_in[1];
  const int* eidx = (const int*)d_in[2];
  const int E = in_sizes[2] / 2;
  const int* src = eidx;
  const int* dst = eidx + E;
  const float* W_mch = (const float*)d_in[3];
  const float* b_mch = (const float*)d_in[4];
  const float* W_mft = (const float*)d_in[5];
  const float* b_mft = (const float*)d_in[6];
  const float* c1m_Wl = (const float*)d_in[7];
  const float* c1m_bl = (const float*)d_in[8];
  const float* c1m_Wr = (const float*)d_in[9];
  const float* c1r_Wl = (const float*)d_in[10];
  const float* c1r_bl = (const float*)d_in[11];
  const float* c1r_Wr = (const float*)d_in[12];
  const float* c2m_Wl = (const float*)d_in[13];
  const float* c2m_bl = (const float*)d_in[14];
  const float* c2m_Wr = (const float*)d_in[15];
  const float* c2r_Wl = (const float*)d_in[16];
  const float* c2r_bl = (const float*)d_in[17];
  const float* c2r_Wr = (const float*)d_in[18];
  const float* ec_W1 = (const float*)d_in[19];
  const float* ec_b1 = (const float*)d_in[20];
  const float* ec_W2 = (const float*)d_in[21];
  const float* ec_b2 = (const float*)d_in[22];

  const int n_mch = in_sizes[0] / D_IN;
  const int n_mft = in_sizes[1] / D_IN;

  // ---- workspace layout ----
  char* ws = (char*)d_ws;
  auto alloc = [&](size_t bytes) {
    char* p = ws;
    ws += (bytes + 255) & ~(size_t)255;
    return p;
  };
  float* h_mch = (float*)alloc((size_t)n_mch * H * 4);
  float* h_mft = (float*)alloc((size_t)n_mft * H * 4);
  float* mch1 = (float*)alloc((size_t)n_mch * H * 4);
  float* mft1 = (float*)alloc((size_t)n_mft * H * 4);
  float* mch2 = (float*)alloc((size_t)n_mch * H * 4);
  float* mft2 = (float*)alloc((size_t)n_mft * H * 4);
  int* off_mch = (int*)alloc(((size_t)n_mch + 1) * 4);
  int* off_mft = (int*)alloc(((size_t)n_mft + 1) * 4);
  int* cur = (int*)alloc(((size_t)n_mch + n_mft) * 4);  // cur_mch | cur_mft
  int* cur_mch = cur;
  int* cur_mft = cur + n_mch;
  int* col_mch = (int*)alloc((size_t)E * 4);
  int* col_mft = (int*)alloc((size_t)E * 4);

  float* out = (float*)d_out;

  // ---- CSR build ----
  hipMemsetAsync(cur, 0, ((size_t)n_mch + n_mft) * 4, stream);
  {
    int blk = (E + 255) / 256;
    degree_kernel<<<blk, 256, 0, stream>>>(src, dst, cur_mch, cur_mft, E);
  }
  scan_kernel<<<2, 1024, 0, stream>>>(cur_mch, off_mch, n_mch, cur_mft, off_mft, n_mft);
  {
    int nmax = n_mch > n_mft ? n_mch : n_mft;
    int blk = (nmax + 255) / 256;
    initcur_kernel<<<blk, 256, 0, stream>>>(off_mch, cur_mch, n_mch, off_mft, cur_mft, n_mft);
  }
  {
    int blk = (E + 255) / 256;
    fill_kernel<<<blk, 256, 0, stream>>>(src, dst, cur_mch, cur_mft, col_mch, col_mft, E);
  }

  // ---- input projections ----
  {
    int blk = ((n_mch * H) + 255) / 256;
    proj_kernel<<<blk, 256, 0, stream>>>(x_mch, W_mch, b_mch, h_mch, n_mch);
    blk = ((n_mft * H) + 255) / 256;
    proj_kernel<<<blk, 256, 0, stream>>>(x_mft, W_mft, b_mft, h_mft, n_mft);
  }

  // ---- conv1 (relu) ----
  {
    int blk_mft = (n_mft + 3) / 4;
    int blk_mch = (n_mch + 3) / 4;
    sage_kernel<true><<<blk_mft, 256, 0, stream>>>(h_mch, h_mft, off_mft, col_mft,
                                                   c1m_Wl, c1m_bl, c1m_Wr, mft1, n_mft);
    sage_kernel<true><<<blk_mch, 256, 0, stream>>>(h_mft, h_mch, off_mch, col_mch,
                                                   c1r_Wl, c1r_bl, c1r_Wr, mch1, n_mch);
    // ---- conv2 (no relu) ----
    sage_kernel<false><<<blk_mft, 256, 0, stream>>>(mch1, mft1, off_mft, col_mft,
                                                    c2m_Wl, c2m_bl, c2m_Wr, mft2, n_mft);
    sage_kernel<false><<<blk_mch, 256, 0, stream>>>(mft1, mch1, off_mch, col_mch,
                                                    c2r_Wl, c2r_bl, c2r_Wr, mch2, n_mch);
  }

  // ---- edge classifier ----
  {
    int blk = (E + 3) / 4;
    edge_mlp_kernel<<<blk, 256, 0, stream>>>(mch2, mft2, src, dst,
                                             ec_W1, ec_b1, ec_W2, ec_b2, out, E);
  }
}

// Round 2
// 844.724 us; speedup vs baseline: 4.2353x; 4.2353x over previous
//
#include <hip/hip_runtime.h>
#include <math.h>

#define D_IN 5
#define H 64

using f32x4 = __attribute__((ext_vector_type(4))) float;
using short8 = __attribute__((ext_vector_type(8))) short;

__device__ inline short f2bf(float f) {
  unsigned u = __builtin_bit_cast(unsigned, f);
  u += 0x7fffu + ((u >> 16) & 1u);  // round-to-nearest-even
  return (short)(u >> 16);
}

__device__ inline short8 cvt8(f32x4 a, f32x4 b) {
  short8 r;
  r[0] = f2bf(a[0]); r[1] = f2bf(a[1]); r[2] = f2bf(a[2]); r[3] = f2bf(a[3]);
  r[4] = f2bf(b[0]); r[5] = f2bf(b[1]); r[6] = f2bf(b[2]); r[7] = f2bf(b[3]);
  return r;
}

// ---------------- input projection: out[i,h] = b[h] + sum_d x[i,d]*W[d,h] ----------------
__global__ __launch_bounds__(256) void proj_kernel(
    const float* __restrict__ x, const float* __restrict__ W,
    const float* __restrict__ b, float* __restrict__ out, int n) {
  __shared__ float Ws[D_IN * H];
  __shared__ float bs[H];
  int t = threadIdx.x;
  for (int i = t; i < D_IN * H; i += 256) Ws[i] = W[i];
  if (t < H) bs[t] = b[t];
  __syncthreads();
  int idx = blockIdx.x * 256 + t;
  int node = idx >> 6;
  int h = idx & 63;
  if (node >= n) return;
  const float* xr = x + (size_t)node * D_IN;
  float acc = bs[h];
#pragma unroll
  for (int d = 0; d < D_IN; ++d) acc = fmaf(xr[d], Ws[d * H + h], acc);
  out[(size_t)node * H + h] = acc;
}

// ---------------- CSR build ----------------
__global__ __launch_bounds__(256) void degree_kernel(
    const int* __restrict__ src, const int* __restrict__ dst,
    int* cur_mch, int* cur_mft, int E) {
  int e = blockIdx.x * 256 + threadIdx.x;
  if (e >= E) return;
  atomicAdd(&cur_mch[src[e]], 1);
  atomicAdd(&cur_mft[dst[e]], 1);
}

__global__ __launch_bounds__(1024) void scan_kernel(
    const int* __restrict__ deg0, int* __restrict__ off0, int n0,
    const int* __restrict__ deg1, int* __restrict__ off1, int n1) {
  const int* deg = blockIdx.x ? deg1 : deg0;
  int* off = blockIdx.x ? off1 : off0;
  int n = blockIdx.x ? n1 : n0;
  __shared__ int tmp[1024];
  __shared__ int carry;
  int t = threadIdx.x;
  if (t == 0) carry = 0;
  __syncthreads();
  for (int base = 0; base < n; base += 1024) {
    int i = base + t;
    int v = (i < n) ? deg[i] : 0;
    tmp[t] = v;
    __syncthreads();
    for (int s = 1; s < 1024; s <<= 1) {
      int add = (t >= s) ? tmp[t - s] : 0;
      __syncthreads();
      tmp[t] += add;
      __syncthreads();
    }
    int incl = tmp[t];
    if (i < n) off[i] = carry + incl - v;
    __syncthreads();
    if (t == 1023) carry = carry + tmp[1023];
    __syncthreads();
  }
  if (t == 0) off[n] = carry;
}

__global__ __launch_bounds__(256) void initcur_kernel(
    const int* __restrict__ off0, int* __restrict__ cur0, int n0,
    const int* __restrict__ off1, int* __restrict__ cur1, int n1) {
  int i = blockIdx.x * 256 + threadIdx.x;
  if (i < n0) cur0[i] = off0[i];
  if (i < n1) cur1[i] = off1[i];
}

__global__ __launch_bounds__(256) void fill_kernel(
    const int* __restrict__ src, const int* __restrict__ dst,
    int* cur_mch, int* cur_mft,
    int* __restrict__ col_mch, int* __restrict__ col_mft, int E) {
  int e = blockIdx.x * 256 + threadIdx.x;
  if (e >= E) return;
  int s = src[e], d = dst[e];
  col_mft[atomicAdd(&cur_mft[d], 1)] = s;   // MFT row d gathers MCH node s
  col_mch[atomicAdd(&cur_mch[s], 1)] = d;   // MCH row s gathers MFT node d
}

// ---------------- fused SAGE via MFMA ----------------
// out = act( [mean | root] @ [Wl;Wr] + bl ), tile = 16 nodes per wave.
// A-frag (16x16x32 bf16): lane holds A[row=lane&15][k = 32*kt + 8*(lane>>4) + j], j=0..7
// C/D: lane,reg r -> D[row=(lane>>4)*4+r][col=lane&15]   [verified mapping]
template <bool RELU>
__global__ __launch_bounds__(256) void sage_mfma_kernel(
    const float* __restrict__ xsrc, const float* __restrict__ xdst,
    const int* __restrict__ off, const int* __restrict__ col,
    const float* __restrict__ Wl, const float* __restrict__ bl,
    const float* __restrict__ Wr,
    float* __restrict__ out, int n_dst) {
  int t = threadIdx.x;
  int wave = t >> 6, lane = t & 63;
  int g = lane >> 4, c = lane & 15;

  // B fragments in registers: B[k][n] = k<64 ? Wl[k][n] : Wr[k-64][n]
  short8 bw[4][4];
#pragma unroll
  for (int kt = 0; kt < 4; ++kt) {
    const float* Wsrc = (kt < 2) ? Wl : Wr;
    int kbase = (kt & 1) * 32 + 8 * g;
#pragma unroll
    for (int n = 0; n < 4; ++n) {
      short8 w;
#pragma unroll
      for (int j = 0; j < 8; ++j)
        w[j] = f2bf(Wsrc[(kbase + j) * H + 16 * n + c]);
      bw[kt][n] = w;
    }
  }
  float blv[4];
#pragma unroll
  for (int n = 0; n < 4; ++n) blv[n] = bl[16 * n + c];

  int node0 = (blockIdx.x * 4 + wave) * 16;
  if (node0 >= n_dst) return;

  int mynode = node0 + c;
  int nd = (mynode < n_dst) ? mynode : 0;

  // mean-aggregate: lane owns node nd, k-chunks [8g,8g+8) and [32+8g,32+8g+8)
  f32x4 zero4 = {0.f, 0.f, 0.f, 0.f};
  f32x4 m0 = zero4, m1 = zero4, m2 = zero4, m3 = zero4;
  int beg = off[nd], end = off[nd + 1];
  for (int j = beg; j < end; ++j) {
    int idx = col[j];
    const f32x4* p = (const f32x4*)(xsrc + (size_t)idx * H + 8 * g);
    m0 += p[0]; m1 += p[1]; m2 += p[8]; m3 += p[9];
  }
  float invd = (end > beg) ? 1.f / (float)(end - beg) : 1.f;
  m0 *= invd; m1 *= invd; m2 *= invd; m3 *= invd;
  const f32x4* pr = (const f32x4*)(xdst + (size_t)nd * H + 8 * g);
  f32x4 r0 = pr[0], r1 = pr[1], r2 = pr[8], r3 = pr[9];

  short8 af[4];
  af[0] = cvt8(m0, m1);   // k in [0,32)   -> Wl rows 0..31
  af[1] = cvt8(m2, m3);   // k in [32,64)  -> Wl rows 32..63
  af[2] = cvt8(r0, r1);   // k in [64,96)  -> Wr rows 0..31
  af[3] = cvt8(r2, r3);   // k in [96,128) -> Wr rows 32..63

  f32x4 acc[4];
#pragma unroll
  for (int n = 0; n < 4; ++n) acc[n] = zero4;
#pragma unroll
  for (int kt = 0; kt < 4; ++kt)
#pragma unroll
    for (int n = 0; n < 4; ++n)
      acc[n] = __builtin_amdgcn_mfma_f32_16x16x32_bf16(af[kt], bw[kt][n], acc[n], 0, 0, 0);

#pragma unroll
  for (int n = 0; n < 4; ++n)
#pragma unroll
    for (int r = 0; r < 4; ++r) {
      float o = acc[n][r] + blv[n];
      if (RELU) o = fmaxf(o, 0.f);
      int row = node0 + 4 * g + r;
      if (row < n_dst) out[(size_t)row * H + 16 * n + c] = o;
    }
}

// ---------------- edge classifier via MFMA ----------------
// A = [mch2[s] | mft2[d]]  (16 edges x 128), B = ec_W1 (128 x 64)
__global__ __launch_bounds__(256) void edge_mlp_mfma_kernel(
    const float* __restrict__ mch2, const float* __restrict__ mft2,
    const int* __restrict__ src, const int* __restrict__ dst,
    const float* __restrict__ W1, const float* __restrict__ b1,
    const float* __restrict__ W2, const float* __restrict__ b2,
    float* __restrict__ out, int E) {
  int t = threadIdx.x;
  int wave = t >> 6, lane = t & 63;
  int g = lane >> 4, c = lane & 15;

  short8 bw[4][4];
#pragma unroll
  for (int kt = 0; kt < 4; ++kt) {
#pragma unroll
    for (int n = 0; n < 4; ++n) {
      short8 w;
#pragma unroll
      for (int j = 0; j < 8; ++j)
        w[j] = f2bf(W1[(32 * kt + 8 * g + j) * H + 16 * n + c]);
      bw[kt][n] = w;
    }
  }
  float b1v[4], w2v[4];
#pragma unroll
  for (int n = 0; n < 4; ++n) { b1v[n] = b1[16 * n + c]; w2v[n] = W2[16 * n + c]; }
  float b2v = b2[0];
  f32x4 zero4 = {0.f, 0.f, 0.f, 0.f};

  int ntiles = (E + 15) >> 4;
  for (int tile = blockIdx.x * 4 + wave; tile < ntiles; tile += gridDim.x * 4) {
    int e0 = tile * 16;
    int e = e0 + c;
    int ee = (e < E) ? e : E - 1;
    int s = src[ee], d = dst[ee];
    const f32x4* pa = (const f32x4*)(mch2 + (size_t)s * H + 8 * g);
    const f32x4* pb = (const f32x4*)(mft2 + (size_t)d * H + 8 * g);
    short8 af[4];
    af[0] = cvt8(pa[0], pa[1]);
    af[1] = cvt8(pa[8], pa[9]);
    af[2] = cvt8(pb[0], pb[1]);
    af[3] = cvt8(pb[8], pb[9]);

    f32x4 acc[4];
#pragma unroll
    for (int n = 0; n < 4; ++n) acc[n] = zero4;
#pragma unroll
    for (int kt = 0; kt < 4; ++kt)
#pragma unroll
      for (int n = 0; n < 4; ++n)
        acc[n] = __builtin_amdgcn_mfma_f32_16x16x32_bf16(af[kt], bw[kt][n], acc[n], 0, 0, 0);

    // per-lane: bias + relu + *W2, then butterfly-reduce the 16 cols (lanes) per row
    float part[4];
#pragma unroll
    for (int r = 0; r < 4; ++r) {
      float sum = 0.f;
#pragma unroll
      for (int n = 0; n < 4; ++n) {
        float v = acc[n][r] + b1v[n];
        v = fmaxf(v, 0.f);
        sum = fmaf(v, w2v[n], sum);
      }
      part[r] = sum;
    }
#pragma unroll
    for (int r = 0; r < 4; ++r) {
      part[r] += __shfl_xor(part[r], 1);
      part[r] += __shfl_xor(part[r], 2);
      part[r] += __shfl_xor(part[r], 4);
      part[r] += __shfl_xor(part[r], 8);
    }
    if (c < 4) {
      int eo = e0 + 4 * g + c;
      float v = (c == 0) ? part[0] : (c == 1) ? part[1] : (c == 2) ? part[2] : part[3];
      if (eo < E) out[eo] = 1.f / (1.f + expf(-(v + b2v)));
    }
  }
}

extern "C" void kernel_launch(void* const* d_in, const int* in_sizes, int n_in,
                              void* d_out, int out_size, void* d_ws, size_t ws_size,
                              hipStream_t stream) {
  const float* x_mch = (const float*)d_in[0];
  const float* x_mft = (const float*)d_in[1];
  const int* eidx = (const int*)d_in[2];
  const int E = in_sizes[2] / 2;
  const int* src = eidx;
  const int* dst = eidx + E;
  const float* W_mch = (const float*)d_in[3];
  const float* b_mch = (const float*)d_in[4];
  const float* W_mft = (const float*)d_in[5];
  const float* b_mft = (const float*)d_in[6];
  const float* c1m_Wl = (const float*)d_in[7];
  const float* c1m_bl = (const float*)d_in[8];
  const float* c1m_Wr = (const float*)d_in[9];
  const float* c1r_Wl = (const float*)d_in[10];
  const float* c1r_bl = (const float*)d_in[11];
  const float* c1r_Wr = (const float*)d_in[12];
  const float* c2m_Wl = (const float*)d_in[13];
  const float* c2m_bl = (const float*)d_in[14];
  const float* c2m_Wr = (const float*)d_in[15];
  const float* c2r_Wl = (const float*)d_in[16];
  const float* c2r_bl = (const float*)d_in[17];
  const float* c2r_Wr = (const float*)d_in[18];
  const float* ec_W1 = (const float*)d_in[19];
  const float* ec_b1 = (const float*)d_in[20];
  const float* ec_W2 = (const float*)d_in[21];
  const float* ec_b2 = (const float*)d_in[22];

  const int n_mch = in_sizes[0] / D_IN;
  const int n_mft = in_sizes[1] / D_IN;

  // ---- workspace layout ----
  char* ws = (char*)d_ws;
  auto alloc = [&](size_t bytes) {
    char* p = ws;
    ws += (bytes + 255) & ~(size_t)255;
    return p;
  };
  float* h_mch = (float*)alloc((size_t)n_mch * H * 4);
  float* h_mft = (float*)alloc((size_t)n_mft * H * 4);
  float* mch1 = (float*)alloc((size_t)n_mch * H * 4);
  float* mft1 = (float*)alloc((size_t)n_mft * H * 4);
  float* mch2 = (float*)alloc((size_t)n_mch * H * 4);
  float* mft2 = (float*)alloc((size_t)n_mft * H * 4);
  int* off_mch = (int*)alloc(((size_t)n_mch + 1) * 4);
  int* off_mft = (int*)alloc(((size_t)n_mft + 1) * 4);
  int* cur = (int*)alloc(((size_t)n_mch + n_mft) * 4);
  int* cur_mch = cur;
  int* cur_mft = cur + n_mch;
  int* col_mch = (int*)alloc((size_t)E * 4);
  int* col_mft = (int*)alloc((size_t)E * 4);

  float* out = (float*)d_out;

  // ---- CSR build ----
  hipMemsetAsync(cur, 0, ((size_t)n_mch + n_mft) * 4, stream);
  {
    int blk = (E + 255) / 256;
    degree_kernel<<<blk, 256, 0, stream>>>(src, dst, cur_mch, cur_mft, E);
  }
  scan_kernel<<<2, 1024, 0, stream>>>(cur_mch, off_mch, n_mch, cur_mft, off_mft, n_mft);
  {
    int nmax = n_mch > n_mft ? n_mch : n_mft;
    int blk = (nmax + 255) / 256;
    initcur_kernel<<<blk, 256, 0, stream>>>(off_mch, cur_mch, n_mch, off_mft, cur_mft, n_mft);
  }
  {
    int blk = (E + 255) / 256;
    fill_kernel<<<blk, 256, 0, stream>>>(src, dst, cur_mch, cur_mft, col_mch, col_mft, E);
  }

  // ---- input projections ----
  {
    int blk = ((n_mch * H) + 255) / 256;
    proj_kernel<<<blk, 256, 0, stream>>>(x_mch, W_mch, b_mch, h_mch, n_mch);
    blk = ((n_mft * H) + 255) / 256;
    proj_kernel<<<blk, 256, 0, stream>>>(x_mft, W_mft, b_mft, h_mft, n_mft);
  }

  // ---- convs (MFMA) ----
  {
    int tiles_mft = (n_mft + 15) / 16;
    int tiles_mch = (n_mch + 15) / 16;
    int blk_mft = (tiles_mft + 3) / 4;
    int blk_mch = (tiles_mch + 3) / 4;
    sage_mfma_kernel<true><<<blk_mft, 256, 0, stream>>>(h_mch, h_mft, off_mft, col_mft,
                                                        c1m_Wl, c1m_bl, c1m_Wr, mft1, n_mft);
    sage_mfma_kernel<true><<<blk_mch, 256, 0, stream>>>(h_mft, h_mch, off_mch, col_mch,
                                                        c1r_Wl, c1r_bl, c1r_Wr, mch1, n_mch);
    sage_mfma_kernel<false><<<blk_mft, 256, 0, stream>>>(mch1, mft1, off_mft, col_mft,
                                                         c2m_Wl, c2m_bl, c2m_Wr, mft2, n_mft);
    sage_mfma_kernel<false><<<blk_mch, 256, 0, stream>>>(mft1, mch1, off_mch, col_mch,
                                                         c2r_Wl, c2r_bl, c2r_Wr, mch2, n_mch);
  }

  // ---- edge classifier (MFMA) ----
  {
    edge_mlp_mfma_kernel<<<2048, 256, 0, stream>>>(mch2, mft2, src, dst,
                                                   ec_W1, ec_b1, ec_W2, ec_b2, out, E);
  }
}

// Round 3
// 598.495 us; speedup vs baseline: 5.9778x; 1.4114x over previous
//
#include <hip/hip_runtime.h>
#include <math.h>

#define D_IN 5
#define H 64

using f32x4 = __attribute__((ext_vector_type(4))) float;
using short8 = __attribute__((ext_vector_type(8))) short;

__device__ inline short f2bf(float f) {
  unsigned u = __builtin_bit_cast(unsigned, f);
  u += 0x7fffu + ((u >> 16) & 1u);  // round-to-nearest-even
  return (short)(u >> 16);
}
__device__ inline float bf2f(short s) {
  return __builtin_bit_cast(float, ((unsigned)(unsigned short)s) << 16);
}
__device__ inline short8 cvt8(f32x4 a, f32x4 b) {
  short8 r;
  r[0] = f2bf(a[0]); r[1] = f2bf(a[1]); r[2] = f2bf(a[2]); r[3] = f2bf(a[3]);
  r[4] = f2bf(b[0]); r[5] = f2bf(b[1]); r[6] = f2bf(b[2]); r[7] = f2bf(b[3]);
  return r;
}

// ---------------- input projection: out[i,h] = bf16( b[h] + sum_d x[i,d]*W[d,h] ) ------
__global__ __launch_bounds__(256) void proj_kernel(
    const float* __restrict__ x, const float* __restrict__ W,
    const float* __restrict__ b, short* __restrict__ out, int n) {
  __shared__ float Ws[D_IN * H];
  __shared__ float bs[H];
  int t = threadIdx.x;
  for (int i = t; i < D_IN * H; i += 256) Ws[i] = W[i];
  if (t < H) bs[t] = b[t];
  __syncthreads();
  int idx = blockIdx.x * 256 + t;
  int node = idx >> 6;
  int h = idx & 63;
  if (node >= n) return;
  const float* xr = x + (size_t)node * D_IN;
  float acc = bs[h];
#pragma unroll
  for (int d = 0; d < D_IN; ++d) acc = fmaf(xr[d], Ws[d * H + h], acc);
  out[(size_t)node * H + h] = f2bf(acc);
}

// ---------------- CSR build ----------------
__global__ __launch_bounds__(256) void degree_kernel(
    const int* __restrict__ src, const int* __restrict__ dst,
    int* cur_mch, int* cur_mft, int E) {
  int e = blockIdx.x * 256 + threadIdx.x;
  if (e >= E) return;
  atomicAdd(&cur_mch[src[e]], 1);
  atomicAdd(&cur_mft[dst[e]], 1);
}

// phase 1: per-block (1024 elems) sums for both degree arrays
__global__ __launch_bounds__(256) void block_sum_kernel(
    const int* __restrict__ deg0, int n0,
    const int* __restrict__ deg1, int n1,
    int* __restrict__ bsum, int nb0) {
  int b = blockIdx.x;
  bool a1 = (b >= nb0);
  const int* deg = a1 ? deg1 : deg0;
  int n = a1 ? n1 : n0;
  int base = (a1 ? b - nb0 : b) * 1024;
  int t = threadIdx.x;
  int s = 0;
#pragma unroll
  for (int i = 0; i < 4; ++i) {
    int idx = base + t * 4 + i;
    if (idx < n) s += deg[idx];
  }
  __shared__ int red[256];
  red[t] = s;
  __syncthreads();
  for (int st = 128; st; st >>= 1) {
    if (t < st) red[t] += red[t + st];
    __syncthreads();
  }
  if (t == 0) bsum[b] = red[0];
}

// phase 2: exclusive-scan the block sums (block 0 -> array0, block 1 -> array1)
__global__ __launch_bounds__(512) void bsum_scan_kernel(int* bsum, int nb0, int nb1) {
  int lo = blockIdx.x ? nb0 : 0;
  int nb = blockIdx.x ? nb1 : nb0;
  __shared__ int tmp[512];
  int t = threadIdx.x;
  int v = (t < nb) ? bsum[lo + t] : 0;
  tmp[t] = v;
  __syncthreads();
  for (int s = 1; s < 512; s <<= 1) {
    int add = (t >= s) ? tmp[t - s] : 0;
    __syncthreads();
    tmp[t] += add;
    __syncthreads();
  }
  if (t < nb) bsum[lo + t] = tmp[t] - v;  // exclusive
}

// phase 3: per-block scan + write off[] and cur[] (=off). deg aliases cur (safe: 1 thread per idx).
__global__ __launch_bounds__(256) void scan_write_kernel(
    const int* __restrict__ deg0, int* __restrict__ off0, int* __restrict__ cur0, int n0,
    const int* __restrict__ deg1, int* __restrict__ off1, int* __restrict__ cur1, int n1,
    const int* __restrict__ bsum, int nb0, int E) {
  int b = blockIdx.x;
  bool a1 = (b >= nb0);
  const int* deg = a1 ? deg1 : deg0;
  int* off = a1 ? off1 : off0;
  int* cur = a1 ? cur1 : cur0;
  int n = a1 ? n1 : n0;
  int base = (a1 ? b - nb0 : b) * 1024;
  int t = threadIdx.x;
  int v[4];
  int s = 0;
#pragma unroll
  for (int i = 0; i < 4; ++i) {
    int idx = base + t * 4 + i;
    v[i] = (idx < n) ? deg[idx] : 0;
    s += v[i];
  }
  __shared__ int tmp[256];
  tmp[t] = s;
  __syncthreads();
  for (int st = 1; st < 256; st <<= 1) {
    int add = (t >= st) ? tmp[t - st] : 0;
    __syncthreads();
    tmp[t] += add;
    __syncthreads();
  }
  int run = bsum[b] + tmp[t] - s;  // exclusive prefix for this thread
#pragma unroll
  for (int i = 0; i < 4; ++i) {
    int idx = base + t * 4 + i;
    if (idx < n) {
      off[idx] = run;
      cur[idx] = run;
      run += v[i];
      if (idx == n - 1) off[n] = E;
    }
  }
}

__global__ __launch_bounds__(256) void fill_kernel(
    const int* __restrict__ src, const int* __restrict__ dst,
    int* cur_mch, int* cur_mft,
    int* __restrict__ col_mch, int* __restrict__ col_mft, int E) {
  int e = blockIdx.x * 256 + threadIdx.x;
  if (e >= E) return;
  int s = src[e], d = dst[e];
  col_mft[atomicAdd(&cur_mft[d], 1)] = s;   // MFT row d gathers MCH node s
  col_mch[atomicAdd(&cur_mch[s], 1)] = d;   // MCH row s gathers MFT node d
}

// ---------------- fused SAGE via MFMA (bf16 features) ----------------
// out = act( [mean | root] @ [Wl;Wr] + bl ), tile = 16 nodes per wave.
// A-frag (16x16x32 bf16): lane holds A[row=lane&15][k = 32*kt + 8*(lane>>4) + j]
// C/D: lane,reg r -> D[row=(lane>>4)*4+r][col=lane&15]
template <bool RELU>
__global__ __launch_bounds__(256) void sage_mfma_kernel(
    const short* __restrict__ xsrc, const short* __restrict__ xdst,
    const int* __restrict__ off, const int* __restrict__ col,
    const float* __restrict__ Wl, const float* __restrict__ bl,
    const float* __restrict__ Wr,
    short* __restrict__ out, int n_dst) {
  int t = threadIdx.x;
  int wave = t >> 6, lane = t & 63;
  int g = lane >> 4, c = lane & 15;

  // B fragments: B[k][n] = k<64 ? Wl[k][n] : Wr[k-64][n]
  short8 bw[4][4];
#pragma unroll
  for (int kt = 0; kt < 4; ++kt) {
    const float* Wsrc = (kt < 2) ? Wl : Wr;
    int kbase = (kt & 1) * 32 + 8 * g;
#pragma unroll
    for (int n = 0; n < 4; ++n) {
      short8 w;
#pragma unroll
      for (int j = 0; j < 8; ++j)
        w[j] = f2bf(Wsrc[(kbase + j) * H + 16 * n + c]);
      bw[kt][n] = w;
    }
  }
  float blv[4];
#pragma unroll
  for (int n = 0; n < 4; ++n) blv[n] = bl[16 * n + c];

  int node0 = (blockIdx.x * 4 + wave) * 16;
  if (node0 >= n_dst) return;

  int mynode = node0 + c;
  int nd = (mynode < n_dst) ? mynode : 0;

  // mean-aggregate in fp32; lane owns feature chunks [8g,8g+8) and [32+8g,32+8g+8)
  float m[16];
#pragma unroll
  for (int i = 0; i < 16; ++i) m[i] = 0.f;
  int beg = off[nd], end = off[nd + 1];
  for (int j = beg; j < end; ++j) {
    int idx = col[j];
    const short8* p = (const short8*)(xsrc + (size_t)idx * H + 8 * g);
    short8 u0 = p[0];
    short8 u1 = p[4];
#pragma unroll
    for (int i = 0; i < 8; ++i) {
      m[i] += bf2f(u0[i]);
      m[8 + i] += bf2f(u1[i]);
    }
  }
  float invd = (end > beg) ? 1.f / (float)(end - beg) : 1.f;
  f32x4 m0, m1, m2, m3;
#pragma unroll
  for (int i = 0; i < 4; ++i) {
    m0[i] = m[i] * invd;
    m1[i] = m[4 + i] * invd;
    m2[i] = m[8 + i] * invd;
    m3[i] = m[12 + i] * invd;
  }
  const short8* pr = (const short8*)(xdst + (size_t)nd * H + 8 * g);

  short8 af[4];
  af[0] = cvt8(m0, m1);  // k in [0,32)   -> Wl rows 0..31
  af[1] = cvt8(m2, m3);  // k in [32,64)  -> Wl rows 32..63
  af[2] = pr[0];         // root, already bf16: k in [64,96)
  af[3] = pr[4];         // k in [96,128)

  f32x4 zero4 = {0.f, 0.f, 0.f, 0.f};
  f32x4 acc[4];
#pragma unroll
  for (int n = 0; n < 4; ++n) acc[n] = zero4;
#pragma unroll
  for (int kt = 0; kt < 4; ++kt)
#pragma unroll
    for (int n = 0; n < 4; ++n)
      acc[n] = __builtin_amdgcn_mfma_f32_16x16x32_bf16(af[kt], bw[kt][n], acc[n], 0, 0, 0);

#pragma unroll
  for (int n = 0; n < 4; ++n)
#pragma unroll
    for (int r = 0; r < 4; ++r) {
      float o = acc[n][r] + blv[n];
      if (RELU) o = fmaxf(o, 0.f);
      int row = node0 + 4 * g + r;
      if (row < n_dst) out[(size_t)row * H + 16 * n + c] = f2bf(o);
    }
}

// ---------------- edge classifier via MFMA (bf16 gathers, zero-convert A) --------------
__global__ __launch_bounds__(256) void edge_mlp_mfma_kernel(
    const short* __restrict__ mch2, const short* __restrict__ mft2,
    const int* __restrict__ src, const int* __restrict__ dst,
    const float* __restrict__ W1, const float* __restrict__ b1,
    const float* __restrict__ W2, const float* __restrict__ b2,
    float* __restrict__ out, int E) {
  int t = threadIdx.x;
  int wave = t >> 6, lane = t & 63;
  int g = lane >> 4, c = lane & 15;

  short8 bw[4][4];
#pragma unroll
  for (int kt = 0; kt < 4; ++kt) {
#pragma unroll
    for (int n = 0; n < 4; ++n) {
      short8 w;
#pragma unroll
      for (int j = 0; j < 8; ++j)
        w[j] = f2bf(W1[(32 * kt + 8 * g + j) * H + 16 * n + c]);
      bw[kt][n] = w;
    }
  }
  float b1v[4], w2v[4];
#pragma unroll
  for (int n = 0; n < 4; ++n) { b1v[n] = b1[16 * n + c]; w2v[n] = W2[16 * n + c]; }
  float b2v = b2[0];
  f32x4 zero4 = {0.f, 0.f, 0.f, 0.f};

  int ntiles = (E + 15) >> 4;
  for (int tile = blockIdx.x * 4 + wave; tile < ntiles; tile += gridDim.x * 4) {
    int e0 = tile * 16;
    int e = e0 + c;
    int ee = (e < E) ? e : E - 1;
    int s = src[ee], d = dst[ee];
    const short8* pa = (const short8*)(mch2 + (size_t)s * H + 8 * g);
    const short8* pb = (const short8*)(mft2 + (size_t)d * H + 8 * g);
    short8 af[4];
    af[0] = pa[0];
    af[1] = pa[4];
    af[2] = pb[0];
    af[3] = pb[4];

    f32x4 acc[4];
#pragma unroll
    for (int n = 0; n < 4; ++n) acc[n] = zero4;
#pragma unroll
    for (int kt = 0; kt < 4; ++kt)
#pragma unroll
      for (int n = 0; n < 4; ++n)
        acc[n] = __builtin_amdgcn_mfma_f32_16x16x32_bf16(af[kt], bw[kt][n], acc[n], 0, 0, 0);

    // bias + relu + *W2, then butterfly-reduce the 16 cols per row
    float part[4];
#pragma unroll
    for (int r = 0; r < 4; ++r) {
      float sum = 0.f;
#pragma unroll
      for (int n = 0; n < 4; ++n) {
        float v = acc[n][r] + b1v[n];
        v = fmaxf(v, 0.f);
        sum = fmaf(v, w2v[n], sum);
      }
      part[r] = sum;
    }
#pragma unroll
    for (int r = 0; r < 4; ++r) {
      part[r] += __shfl_xor(part[r], 1);
      part[r] += __shfl_xor(part[r], 2);
      part[r] += __shfl_xor(part[r], 4);
      part[r] += __shfl_xor(part[r], 8);
    }
    if (c < 4) {
      int eo = e0 + 4 * g + c;
      float v = (c == 0) ? part[0] : (c == 1) ? part[1] : (c == 2) ? part[2] : part[3];
      if (eo < E) out[eo] = 1.f / (1.f + expf(-(v + b2v)));
    }
  }
}

extern "C" void kernel_launch(void* const* d_in, const int* in_sizes, int n_in,
                              void* d_out, int out_size, void* d_ws, size_t ws_size,
                              hipStream_t stream) {
  const float* x_mch = (const float*)d_in[0];
  const float* x_mft = (const float*)d_in[1];
  const int* eidx = (const int*)d_in[2];
  const int E = in_sizes[2] / 2;
  const int* src = eidx;
  const int* dst = eidx + E;
  const float* W_mch = (const float*)d_in[3];
  const float* b_mch = (const float*)d_in[4];
  const float* W_mft = (const float*)d_in[5];
  const float* b_mft = (const float*)d_in[6];
  const float* c1m_Wl = (const float*)d_in[7];
  const float* c1m_bl = (const float*)d_in[8];
  const float* c1m_Wr = (const float*)d_in[9];
  const float* c1r_Wl = (const float*)d_in[10];
  const float* c1r_bl = (const float*)d_in[11];
  const float* c1r_Wr = (const float*)d_in[12];
  const float* c2m_Wl = (const float*)d_in[13];
  const float* c2m_bl = (const float*)d_in[14];
  const float* c2m_Wr = (const float*)d_in[15];
  const float* c2r_Wl = (const float*)d_in[16];
  const float* c2r_bl = (const float*)d_in[17];
  const float* c2r_Wr = (const float*)d_in[18];
  const float* ec_W1 = (const float*)d_in[19];
  const float* ec_b1 = (const float*)d_in[20];
  const float* ec_W2 = (const float*)d_in[21];
  const float* ec_b2 = (const float*)d_in[22];

  const int n_mch = in_sizes[0] / D_IN;
  const int n_mft = in_sizes[1] / D_IN;

  // ---- workspace layout ----
  char* ws = (char*)d_ws;
  auto alloc = [&](size_t bytes) {
    char* p = ws;
    ws += (bytes + 255) & ~(size_t)255;
    return p;
  };
  short* h_mch = (short*)alloc((size_t)n_mch * H * 2);
  short* h_mft = (short*)alloc((size_t)n_mft * H * 2);
  short* mch1 = (short*)alloc((size_t)n_mch * H * 2);
  short* mft1 = (short*)alloc((size_t)n_mft * H * 2);
  short* mch2 = (short*)alloc((size_t)n_mch * H * 2);
  short* mft2 = (short*)alloc((size_t)n_mft * H * 2);
  int* off_mch = (int*)alloc(((size_t)n_mch + 1) * 4);
  int* off_mft = (int*)alloc(((size_t)n_mft + 1) * 4);
  int* cur = (int*)alloc(((size_t)n_mch + n_mft) * 4);
  int* cur_mch = cur;
  int* cur_mft = cur + n_mch;
  int* col_mch = (int*)alloc((size_t)E * 4);
  int* col_mft = (int*)alloc((size_t)E * 4);
  const int nb_mch = (n_mch + 1023) / 1024;
  const int nb_mft = (n_mft + 1023) / 1024;
  int* bsum = (int*)alloc(((size_t)nb_mch + nb_mft) * 4);

  float* out = (float*)d_out;

  // ---- CSR build ----
  hipMemsetAsync(cur, 0, ((size_t)n_mch + n_mft) * 4, stream);
  {
    int blk = (E + 255) / 256;
    degree_kernel<<<blk, 256, 0, stream>>>(src, dst, cur_mch, cur_mft, E);
  }
  block_sum_kernel<<<nb_mch + nb_mft, 256, 0, stream>>>(cur_mch, n_mch, cur_mft, n_mft,
                                                        bsum, nb_mch);
  bsum_scan_kernel<<<2, 512, 0, stream>>>(bsum, nb_mch, nb_mft);
  scan_write_kernel<<<nb_mch + nb_mft, 256, 0, stream>>>(
      cur_mch, off_mch, cur_mch, n_mch, cur_mft, off_mft, cur_mft, n_mft, bsum, nb_mch, E);
  {
    int blk = (E + 255) / 256;
    fill_kernel<<<blk, 256, 0, stream>>>(src, dst, cur_mch, cur_mft, col_mch, col_mft, E);
  }

  // ---- input projections ----
  {
    int blk = ((n_mch * H) + 255) / 256;
    proj_kernel<<<blk, 256, 0, stream>>>(x_mch, W_mch, b_mch, h_mch, n_mch);
    blk = ((n_mft * H) + 255) / 256;
    proj_kernel<<<blk, 256, 0, stream>>>(x_mft, W_mft, b_mft, h_mft, n_mft);
  }

  // ---- convs (MFMA) ----
  {
    int tiles_mft = (n_mft + 15) / 16;
    int tiles_mch = (n_mch + 15) / 16;
    int blk_mft = (tiles_mft + 3) / 4;
    int blk_mch = (tiles_mch + 3) / 4;
    sage_mfma_kernel<true><<<blk_mft, 256, 0, stream>>>(h_mch, h_mft, off_mft, col_mft,
                                                        c1m_Wl, c1m_bl, c1m_Wr, mft1, n_mft);
    sage_mfma_kernel<true><<<blk_mch, 256, 0, stream>>>(h_mft, h_mch, off_mch, col_mch,
                                                        c1r_Wl, c1r_bl, c1r_Wr, mch1, n_mch);
    sage_mfma_kernel<false><<<blk_mft, 256, 0, stream>>>(mch1, mft1, off_mft, col_mft,
                                                         c2m_Wl, c2m_bl, c2m_Wr, mft2, n_mft);
    sage_mfma_kernel<false><<<blk_mch, 256, 0, stream>>>(mft1, mch1, off_mch, col_mch,
                                                         c2r_Wl, c2r_bl, c2r_Wr, mch2, n_mch);
  }

  // ---- edge classifier (MFMA) ----
  {
    edge_mlp_mfma_kernel<<<2048, 256, 0, stream>>>(mch2, mft2, src, dst,
                                                   ec_W1, ec_b1, ec_W2, ec_b2, out, E);
  }
}

// Round 4
// 483.256 us; speedup vs baseline: 7.4033x; 1.2385x over previous
//
#include <hip/hip_runtime.h>
#include <math.h>

#define D_IN 5
#define H 64

using f32x4 = __attribute__((ext_vector_type(4))) float;
using short8 = __attribute__((ext_vector_type(8))) short;

__device__ inline short f2bf(float f) {
  unsigned u = __builtin_bit_cast(unsigned, f);
  u += 0x7fffu + ((u >> 16) & 1u);  // round-to-nearest-even
  return (short)(u >> 16);
}
__device__ inline float bf2f(short s) {
  return __builtin_bit_cast(float, ((unsigned)(unsigned short)s) << 16);
}
__device__ inline short8 cvt8(f32x4 a, f32x4 b) {
  short8 r;
  r[0] = f2bf(a[0]); r[1] = f2bf(a[1]); r[2] = f2bf(a[2]); r[3] = f2bf(a[3]);
  r[4] = f2bf(b[0]); r[5] = f2bf(b[1]); r[6] = f2bf(b[2]); r[7] = f2bf(b[3]);
  return r;
}

// ---------------- input projection ----------------
__global__ __launch_bounds__(256) void proj_kernel(
    const float* __restrict__ x, const float* __restrict__ W,
    const float* __restrict__ b, short* __restrict__ out, int n) {
  __shared__ float Ws[D_IN * H];
  __shared__ float bs[H];
  int t = threadIdx.x;
  for (int i = t; i < D_IN * H; i += 256) Ws[i] = W[i];
  if (t < H) bs[t] = b[t];
  __syncthreads();
  int idx = blockIdx.x * 256 + t;
  int node = idx >> 6;
  int h = idx & 63;
  if (node >= n) return;
  const float* xr = x + (size_t)node * D_IN;
  float acc = bs[h];
#pragma unroll
  for (int d = 0; d < D_IN; ++d) acc = fmaf(xr[d], Ws[d * H + h], acc);
  out[(size_t)node * H + h] = f2bf(acc);
}

// ---------------- CSR build ----------------
__global__ __launch_bounds__(256) void degree_kernel(
    const int* __restrict__ src, const int* __restrict__ dst,
    int* cur_mch, int* cur_mft, int E) {
  int e0 = (blockIdx.x * 256 + threadIdx.x) * 4;
  if (e0 >= E) return;
  if (e0 + 4 <= E) {
    int4 s4 = *(const int4*)(src + e0);
    int4 d4 = *(const int4*)(dst + e0);
    atomicAdd(&cur_mch[s4.x], 1);
    atomicAdd(&cur_mch[s4.y], 1);
    atomicAdd(&cur_mch[s4.z], 1);
    atomicAdd(&cur_mch[s4.w], 1);
    atomicAdd(&cur_mft[d4.x], 1);
    atomicAdd(&cur_mft[d4.y], 1);
    atomicAdd(&cur_mft[d4.z], 1);
    atomicAdd(&cur_mft[d4.w], 1);
  } else {
    for (int i = 0; i < 4; ++i) {
      int e = e0 + i;
      if (e < E) {
        atomicAdd(&cur_mch[src[e]], 1);
        atomicAdd(&cur_mft[dst[e]], 1);
      }
    }
  }
}

// phase 1: per-block (1024 elems) sums for both degree arrays
__global__ __launch_bounds__(256) void block_sum_kernel(
    const int* __restrict__ deg0, int n0,
    const int* __restrict__ deg1, int n1,
    int* __restrict__ bsum, int nb0) {
  int b = blockIdx.x;
  bool a1 = (b >= nb0);
  const int* deg = a1 ? deg1 : deg0;
  int n = a1 ? n1 : n0;
  int base = (a1 ? b - nb0 : b) * 1024;
  int t = threadIdx.x;
  int s = 0;
#pragma unroll
  for (int i = 0; i < 4; ++i) {
    int idx = base + t * 4 + i;
    if (idx < n) s += deg[idx];
  }
  __shared__ int red[256];
  red[t] = s;
  __syncthreads();
  for (int st = 128; st; st >>= 1) {
    if (t < st) red[t] += red[t + st];
    __syncthreads();
  }
  if (t == 0) bsum[b] = red[0];
}

// phase 2: exclusive-scan the block sums
__global__ __launch_bounds__(512) void bsum_scan_kernel(int* bsum, int nb0, int nb1) {
  int lo = blockIdx.x ? nb0 : 0;
  int nb = blockIdx.x ? nb1 : nb0;
  __shared__ int tmp[512];
  int t = threadIdx.x;
  int v = (t < nb) ? bsum[lo + t] : 0;
  tmp[t] = v;
  __syncthreads();
  for (int s = 1; s < 512; s <<= 1) {
    int add = (t >= s) ? tmp[t - s] : 0;
    __syncthreads();
    tmp[t] += add;
    __syncthreads();
  }
  if (t < nb) bsum[lo + t] = tmp[t] - v;  // exclusive
}

// phase 3: per-block scan + write off[] and cur[] (=off). deg aliases cur.
__global__ __launch_bounds__(256) void scan_write_kernel(
    const int* __restrict__ deg0, int* __restrict__ off0, int* __restrict__ cur0, int n0,
    const int* __restrict__ deg1, int* __restrict__ off1, int* __restrict__ cur1, int n1,
    const int* __restrict__ bsum, int nb0, int E) {
  int b = blockIdx.x;
  bool a1 = (b >= nb0);
  const int* deg = a1 ? deg1 : deg0;
  int* off = a1 ? off1 : off0;
  int* cur = a1 ? cur1 : cur0;
  int n = a1 ? n1 : n0;
  int base = (a1 ? b - nb0 : b) * 1024;
  int t = threadIdx.x;
  int v[4];
  int s = 0;
#pragma unroll
  for (int i = 0; i < 4; ++i) {
    int idx = base + t * 4 + i;
    v[i] = (idx < n) ? deg[idx] : 0;
    s += v[i];
  }
  __shared__ int tmp[256];
  tmp[t] = s;
  __syncthreads();
  for (int st = 1; st < 256; st <<= 1) {
    int add = (t >= st) ? tmp[t - st] : 0;
    __syncthreads();
    tmp[t] += add;
    __syncthreads();
  }
  int run = bsum[b] + tmp[t] - s;
#pragma unroll
  for (int i = 0; i < 4; ++i) {
    int idx = base + t * 4 + i;
    if (idx < n) {
      off[idx] = run;
      cur[idx] = run;
      run += v[i];
      if (idx == n - 1) off[n] = E;
    }
  }
}

// fill with 4-edge ILP: issue all 8 atomics before dependent stores
__global__ __launch_bounds__(256) void fill_kernel(
    const int* __restrict__ src, const int* __restrict__ dst,
    int* cur_mch, int* cur_mft,
    int* __restrict__ col_mch, int* __restrict__ col_mft, int E) {
  int e0 = (blockIdx.x * 256 + threadIdx.x) * 4;
  if (e0 >= E) return;
  if (e0 + 4 <= E) {
    int4 s4 = *(const int4*)(src + e0);
    int4 d4 = *(const int4*)(dst + e0);
    int pf0 = atomicAdd(&cur_mft[d4.x], 1);
    int pf1 = atomicAdd(&cur_mft[d4.y], 1);
    int pf2 = atomicAdd(&cur_mft[d4.z], 1);
    int pf3 = atomicAdd(&cur_mft[d4.w], 1);
    int pm0 = atomicAdd(&cur_mch[s4.x], 1);
    int pm1 = atomicAdd(&cur_mch[s4.y], 1);
    int pm2 = atomicAdd(&cur_mch[s4.z], 1);
    int pm3 = atomicAdd(&cur_mch[s4.w], 1);
    col_mft[pf0] = s4.x;
    col_mft[pf1] = s4.y;
    col_mft[pf2] = s4.z;
    col_mft[pf3] = s4.w;
    col_mch[pm0] = d4.x;
    col_mch[pm1] = d4.y;
    col_mch[pm2] = d4.z;
    col_mch[pm3] = d4.w;
  } else {
    for (int i = 0; i < 4; ++i) {
      int e = e0 + i;
      if (e < E) {
        int s = src[e], d = dst[e];
        col_mft[atomicAdd(&cur_mft[d], 1)] = s;
        col_mch[atomicAdd(&cur_mch[s], 1)] = d;
      }
    }
  }
}

// ---------------- fused SAGE via MFMA (bf16 feats), both directions in one launch ------
// blocks [0, blkA): side A;  [blkA, ...): side B
template <bool RELU>
__global__ __launch_bounds__(256) void sage_dual_kernel(
    const short* __restrict__ xsrcA, const short* __restrict__ xdstA,
    const int* __restrict__ offA, const int* __restrict__ colA,
    const float* __restrict__ WlA, const float* __restrict__ blA,
    const float* __restrict__ WrA, short* __restrict__ outA, int nA, int blkA,
    const short* __restrict__ xsrcB, const short* __restrict__ xdstB,
    const int* __restrict__ offB, const int* __restrict__ colB,
    const float* __restrict__ WlB, const float* __restrict__ blB,
    const float* __restrict__ WrB, short* __restrict__ outB, int nB) {
  bool isB = ((int)blockIdx.x >= blkA);
  int bid = isB ? (int)blockIdx.x - blkA : (int)blockIdx.x;
  const short* xsrc = isB ? xsrcB : xsrcA;
  const short* xdst = isB ? xdstB : xdstA;
  const int* off = isB ? offB : offA;
  const int* col = isB ? colB : colA;
  const float* Wl = isB ? WlB : WlA;
  const float* bl = isB ? blB : blA;
  const float* Wr = isB ? WrB : WrA;
  short* out = isB ? outB : outA;
  int n_dst = isB ? nB : nA;

  int t = threadIdx.x;
  int wave = t >> 6, lane = t & 63;
  int g = lane >> 4, c = lane & 15;

  // B fragments: B[k][n] = k<64 ? Wl[k][n] : Wr[k-64][n]
  short8 bw[4][4];
#pragma unroll
  for (int kt = 0; kt < 4; ++kt) {
    const float* Wsrc = (kt < 2) ? Wl : Wr;
    int kbase = (kt & 1) * 32 + 8 * g;
#pragma unroll
    for (int n = 0; n < 4; ++n) {
      short8 w;
#pragma unroll
      for (int j = 0; j < 8; ++j)
        w[j] = f2bf(Wsrc[(kbase + j) * H + 16 * n + c]);
      bw[kt][n] = w;
    }
  }
  float blv[4];
#pragma unroll
  for (int n = 0; n < 4; ++n) blv[n] = bl[16 * n + c];

  int node0 = (bid * 4 + wave) * 16;
  if (node0 >= n_dst) return;

  int mynode = node0 + c;
  int nd = (mynode < n_dst) ? mynode : 0;

  // mean-aggregate in fp32 with 2-deep software pipeline
  float m[16];
#pragma unroll
  for (int i = 0; i < 16; ++i) m[i] = 0.f;
  int beg = off[nd], end = off[nd + 1];
  int n_nb = end - beg;
  if (n_nb > 0) {
    int idx_c = col[beg];
    int idx_n = (n_nb > 1) ? col[beg + 1] : 0;
    const short8* pc = (const short8*)(xsrc + (size_t)idx_c * H + 8 * g);
    short8 u0 = pc[0], u1 = pc[4];
    for (int j = 1; j < n_nb; ++j) {
      int idx_n2 = (j + 1 < n_nb) ? col[beg + j + 1] : 0;
      const short8* pn = (const short8*)(xsrc + (size_t)idx_n * H + 8 * g);
      short8 v0 = pn[0], v1 = pn[4];
#pragma unroll
      for (int i = 0; i < 8; ++i) {
        m[i] += bf2f(u0[i]);
        m[8 + i] += bf2f(u1[i]);
      }
      u0 = v0;
      u1 = v1;
      idx_n = idx_n2;
    }
#pragma unroll
    for (int i = 0; i < 8; ++i) {
      m[i] += bf2f(u0[i]);
      m[8 + i] += bf2f(u1[i]);
    }
  }
  float invd = (n_nb > 0) ? 1.f / (float)n_nb : 1.f;
  f32x4 m0, m1, m2, m3;
#pragma unroll
  for (int i = 0; i < 4; ++i) {
    m0[i] = m[i] * invd;
    m1[i] = m[4 + i] * invd;
    m2[i] = m[8 + i] * invd;
    m3[i] = m[12 + i] * invd;
  }
  const short8* pr = (const short8*)(xdst + (size_t)nd * H + 8 * g);

  short8 af[4];
  af[0] = cvt8(m0, m1);  // k [0,32)   -> Wl rows 0..31
  af[1] = cvt8(m2, m3);  // k [32,64)  -> Wl rows 32..63
  af[2] = pr[0];         // root bf16: k [64,96)
  af[3] = pr[4];         // k [96,128)

  f32x4 zero4 = {0.f, 0.f, 0.f, 0.f};
  f32x4 acc[4];
#pragma unroll
  for (int n = 0; n < 4; ++n) acc[n] = zero4;
#pragma unroll
  for (int kt = 0; kt < 4; ++kt)
#pragma unroll
    for (int n = 0; n < 4; ++n)
      acc[n] = __builtin_amdgcn_mfma_f32_16x16x32_bf16(af[kt], bw[kt][n], acc[n], 0, 0, 0);

#pragma unroll
  for (int n = 0; n < 4; ++n)
#pragma unroll
    for (int r = 0; r < 4; ++r) {
      float o = acc[n][r] + blv[n];
      if (RELU) o = fmaxf(o, 0.f);
      int row = node0 + 4 * g + r;
      if (row < n_dst) out[(size_t)row * H + 16 * n + c] = f2bf(o);
    }
}

// ---------------- edge classifier via MFMA (bf16 gathers) --------------
__global__ __launch_bounds__(256) void edge_mlp_mfma_kernel(
    const short* __restrict__ mch2, const short* __restrict__ mft2,
    const int* __restrict__ src, const int* __restrict__ dst,
    const float* __restrict__ W1, const float* __restrict__ b1,
    const float* __restrict__ W2, const float* __restrict__ b2,
    float* __restrict__ out, int E) {
  int t = threadIdx.x;
  int wave = t >> 6, lane = t & 63;
  int g = lane >> 4, c = lane & 15;

  short8 bw[4][4];
#pragma unroll
  for (int kt = 0; kt < 4; ++kt) {
#pragma unroll
    for (int n = 0; n < 4; ++n) {
      short8 w;
#pragma unroll
      for (int j = 0; j < 8; ++j)
        w[j] = f2bf(W1[(32 * kt + 8 * g + j) * H + 16 * n + c]);
      bw[kt][n] = w;
    }
  }
  float b1v[4], w2v[4];
#pragma unroll
  for (int n = 0; n < 4; ++n) { b1v[n] = b1[16 * n + c]; w2v[n] = W2[16 * n + c]; }
  float b2v = b2[0];
  f32x4 zero4 = {0.f, 0.f, 0.f, 0.f};

  int ntiles = (E + 15) >> 4;
  for (int tile = blockIdx.x * 4 + wave; tile < ntiles; tile += gridDim.x * 4) {
    int e0 = tile * 16;
    int e = e0 + c;
    int ee = (e < E) ? e : E - 1;
    int s = src[ee], d = dst[ee];
    const short8* pa = (const short8*)(mch2 + (size_t)s * H + 8 * g);
    const short8* pb = (const short8*)(mft2 + (size_t)d * H + 8 * g);
    short8 af[4];
    af[0] = pa[0];
    af[1] = pa[4];
    af[2] = pb[0];
    af[3] = pb[4];

    f32x4 acc[4];
#pragma unroll
    for (int n = 0; n < 4; ++n) acc[n] = zero4;
#pragma unroll
    for (int kt = 0; kt < 4; ++kt)
#pragma unroll
      for (int n = 0; n < 4; ++n)
        acc[n] = __builtin_amdgcn_mfma_f32_16x16x32_bf16(af[kt], bw[kt][n], acc[n], 0, 0, 0);

    float part[4];
#pragma unroll
    for (int r = 0; r < 4; ++r) {
      float sum = 0.f;
#pragma unroll
      for (int n = 0; n < 4; ++n) {
        float v = acc[n][r] + b1v[n];
        v = fmaxf(v, 0.f);
        sum = fmaf(v, w2v[n], sum);
      }
      part[r] = sum;
    }
#pragma unroll
    for (int r = 0; r < 4; ++r) {
      part[r] += __shfl_xor(part[r], 1);
      part[r] += __shfl_xor(part[r], 2);
      part[r] += __shfl_xor(part[r], 4);
      part[r] += __shfl_xor(part[r], 8);
    }
    if (c < 4) {
      int eo = e0 + 4 * g + c;
      float v = (c == 0) ? part[0] : (c == 1) ? part[1] : (c == 2) ? part[2] : part[3];
      if (eo < E) out[eo] = 1.f / (1.f + expf(-(v + b2v)));
    }
  }
}

extern "C" void kernel_launch(void* const* d_in, const int* in_sizes, int n_in,
                              void* d_out, int out_size, void* d_ws, size_t ws_size,
                              hipStream_t stream) {
  const float* x_mch = (const float*)d_in[0];
  const float* x_mft = (const float*)d_in[1];
  const int* eidx = (const int*)d_in[2];
  const int E = in_sizes[2] / 2;
  const int* src = eidx;
  const int* dst = eidx + E;
  const float* W_mch = (const float*)d_in[3];
  const float* b_mch = (const float*)d_in[4];
  const float* W_mft = (const float*)d_in[5];
  const float* b_mft = (const float*)d_in[6];
  const float* c1m_Wl = (const float*)d_in[7];
  const float* c1m_bl = (const float*)d_in[8];
  const float* c1m_Wr = (const float*)d_in[9];
  const float* c1r_Wl = (const float*)d_in[10];
  const float* c1r_bl = (const float*)d_in[11];
  const float* c1r_Wr = (const float*)d_in[12];
  const float* c2m_Wl = (const float*)d_in[13];
  const float* c2m_bl = (const float*)d_in[14];
  const float* c2m_Wr = (const float*)d_in[15];
  const float* c2r_Wl = (const float*)d_in[16];
  const float* c2r_bl = (const float*)d_in[17];
  const float* c2r_Wr = (const float*)d_in[18];
  const float* ec_W1 = (const float*)d_in[19];
  const float* ec_b1 = (const float*)d_in[20];
  const float* ec_W2 = (const float*)d_in[21];
  const float* ec_b2 = (const float*)d_in[22];

  const int n_mch = in_sizes[0] / D_IN;
  const int n_mft = in_sizes[1] / D_IN;

  // ---- workspace layout ----
  char* ws = (char*)d_ws;
  auto alloc = [&](size_t bytes) {
    char* p = ws;
    ws += (bytes + 255) & ~(size_t)255;
    return p;
  };
  short* h_mch = (short*)alloc((size_t)n_mch * H * 2);
  short* h_mft = (short*)alloc((size_t)n_mft * H * 2);
  short* mch1 = (short*)alloc((size_t)n_mch * H * 2);
  short* mft1 = (short*)alloc((size_t)n_mft * H * 2);
  short* mch2 = (short*)alloc((size_t)n_mch * H * 2);
  short* mft2 = (short*)alloc((size_t)n_mft * H * 2);
  int* off_mch = (int*)alloc(((size_t)n_mch + 1) * 4);
  int* off_mft = (int*)alloc(((size_t)n_mft + 1) * 4);
  int* cur = (int*)alloc(((size_t)n_mch + n_mft) * 4);
  int* cur_mch = cur;
  int* cur_mft = cur + n_mch;
  int* col_mch = (int*)alloc((size_t)E * 4);
  int* col_mft = (int*)alloc((size_t)E * 4);
  const int nb_mch = (n_mch + 1023) / 1024;
  const int nb_mft = (n_mft + 1023) / 1024;
  int* bsum = (int*)alloc(((size_t)nb_mch + nb_mft) * 4);

  float* out = (float*)d_out;

  // ---- CSR build ----
  hipMemsetAsync(cur, 0, ((size_t)n_mch + n_mft) * 4, stream);
  {
    int blk = (E + 1023) / 1024;
    degree_kernel<<<blk, 256, 0, stream>>>(src, dst, cur_mch, cur_mft, E);
  }
  block_sum_kernel<<<nb_mch + nb_mft, 256, 0, stream>>>(cur_mch, n_mch, cur_mft, n_mft,
                                                        bsum, nb_mch);
  bsum_scan_kernel<<<2, 512, 0, stream>>>(bsum, nb_mch, nb_mft);
  scan_write_kernel<<<nb_mch + nb_mft, 256, 0, stream>>>(
      cur_mch, off_mch, cur_mch, n_mch, cur_mft, off_mft, cur_mft, n_mft, bsum, nb_mch, E);
  {
    int blk = (E + 1023) / 1024;
    fill_kernel<<<blk, 256, 0, stream>>>(src, dst, cur_mch, cur_mft, col_mch, col_mft, E);
  }

  // ---- input projections ----
  {
    int blk = ((n_mch * H) + 255) / 256;
    proj_kernel<<<blk, 256, 0, stream>>>(x_mch, W_mch, b_mch, h_mch, n_mch);
    blk = ((n_mft * H) + 255) / 256;
    proj_kernel<<<blk, 256, 0, stream>>>(x_mft, W_mft, b_mft, h_mft, n_mft);
  }

  // ---- convs (MFMA, both directions per launch) ----
  {
    int tiles_mft = (n_mft + 15) / 16;
    int tiles_mch = (n_mch + 15) / 16;
    int blkA = (tiles_mft + 3) / 4;
    int blkB = (tiles_mch + 3) / 4;
    sage_dual_kernel<true><<<blkA + blkB, 256, 0, stream>>>(
        h_mch, h_mft, off_mft, col_mft, c1m_Wl, c1m_bl, c1m_Wr, mft1, n_mft, blkA,
        h_mft, h_mch, off_mch, col_mch, c1r_Wl, c1r_bl, c1r_Wr, mch1, n_mch);
    sage_dual_kernel<false><<<blkA + blkB, 256, 0, stream>>>(
        mch1, mft1, off_mft, col_mft, c2m_Wl, c2m_bl, c2m_Wr, mft2, n_mft, blkA,
        mft1, mch1, off_mch, col_mch, c2r_Wl, c2r_bl, c2r_Wr, mch2, n_mch);
  }

  // ---- edge classifier (MFMA) ----
  {
    edge_mlp_mfma_kernel<<<2048, 256, 0, stream>>>(mch2, mft2, src, dst,
                                                   ec_W1, ec_b1, ec_W2, ec_b2, out, E);
  }
}